// Round 1
// baseline (18833.421 us; speedup 1.0000x reference)
//
#include <hip/hip_runtime.h>
#include <math.h>

#define B_DIM 4
#define T_DIM 4096
#define C_DIM 1024
#define BT    (B_DIM*T_DIM)              // 16384
#define BTC   ((size_t)BT*(size_t)C_DIM) // 16777216

// ---------------------------------------------------------------------------
// Generic fp32 tiled matmul body (shared by single and batched wrappers).
//   TB=1: C[m,n] = sum_k A[m,k]*B[n,k]      (B stored [N,K] row-major)
//   TB=0: C[m,n] = sum_k A[m,k]*B[k,n]
//   HAS_A2: A_eff[m,k] = A[m,k]*A2[m,k]
//   out = alpha*acc + (HAS_D ? beta*D[m,n] : 0)
// ---------------------------------------------------------------------------
template<int BM, int BN, int BK, int TM, int TN, bool TB, bool HAS_A2, bool HAS_D>
__device__ __forceinline__ void mm_body(const float* __restrict__ A,
                                        const float* __restrict__ Bmat,
                                        const float* __restrict__ A2,
                                        const float* __restrict__ Dmat,
                                        float* __restrict__ C,
                                        int M, int N, int K, float alpha, float beta)
{
    constexpr int NG = TN / 4;
    __shared__ float As[BK][BM + 4];
    __shared__ float Bs[BK][BN + 4];

    const int tid = threadIdx.x;
    const int m0 = blockIdx.y * BM;
    const int n0 = blockIdx.x * BN;
    const int tx = tid & 15;
    const int ty = tid >> 4;

    float acc[TM][TN];
#pragma unroll
    for (int i = 0; i < TM; ++i)
#pragma unroll
        for (int j = 0; j < TN; ++j) acc[i][j] = 0.f;

    for (int k0 = 0; k0 < K; k0 += BK) {
        {
            const int r0 = tid >> 2;
            const int kq = (tid & 3) * 4;
#pragma unroll
            for (int r = 0; r < BM; r += 64) {
                const int row = r + r0;
                float4 a = *(const float4*)(A + (size_t)(m0 + row) * K + k0 + kq);
                if (HAS_A2) {
                    float4 a2 = *(const float4*)(A2 + (size_t)(m0 + row) * K + k0 + kq);
                    a.x *= a2.x; a.y *= a2.y; a.z *= a2.z; a.w *= a2.w;
                }
                As[kq + 0][row] = a.x; As[kq + 1][row] = a.y;
                As[kq + 2][row] = a.z; As[kq + 3][row] = a.w;
            }
        }
        if (TB) {
            const int r0 = tid >> 2;
            const int kq = (tid & 3) * 4;
#pragma unroll
            for (int r = 0; r < BN; r += 64) {
                const int row = r + r0;
                float4 b = *(const float4*)(Bmat + (size_t)(n0 + row) * K + k0 + kq);
                Bs[kq + 0][row] = b.x; Bs[kq + 1][row] = b.y;
                Bs[kq + 2][row] = b.z; Bs[kq + 3][row] = b.w;
            }
        } else {
            constexpr int CPR = BN / 4;
            constexpr int RPP = 256 / CPR;
            const int rr = tid / CPR;
            const int cc = (tid % CPR) * 4;
#pragma unroll
            for (int r = 0; r < BK; r += RPP) {
                float4 b = *(const float4*)(Bmat + (size_t)(k0 + r + rr) * N + n0 + cc);
                *(float4*)(&Bs[r + rr][cc]) = b;
            }
        }
        __syncthreads();

#pragma unroll
        for (int kk = 0; kk < BK; ++kk) {
            float a[TM], b[TN];
#pragma unroll
            for (int i = 0; i < TM; i += 4)
                *(float4*)(&a[i]) = *(const float4*)(&As[kk][ty * TM + i]);
#pragma unroll
            for (int g = 0; g < NG; ++g)
                *(float4*)(&b[g * 4]) = *(const float4*)(&Bs[kk][g * (BN / 2) + tx * 4]);
#pragma unroll
            for (int i = 0; i < TM; ++i)
#pragma unroll
                for (int j = 0; j < TN; ++j)
                    acc[i][j] = fmaf(a[i], b[j], acc[i][j]);
        }
        __syncthreads();
    }

#pragma unroll
    for (int i = 0; i < TM; ++i) {
        const size_t rbase = (size_t)(m0 + ty * TM + i) * N + n0;
#pragma unroll
        for (int g = 0; g < NG; ++g) {
            const size_t cb = rbase + g * (BN / 2) + tx * 4;
            float4 o;
            o.x = alpha * acc[i][g * 4 + 0];
            o.y = alpha * acc[i][g * 4 + 1];
            o.z = alpha * acc[i][g * 4 + 2];
            o.w = alpha * acc[i][g * 4 + 3];
            if (HAS_D) {
                float4 d4 = *(const float4*)(Dmat + cb);
                o.x = fmaf(beta, d4.x, o.x); o.y = fmaf(beta, d4.y, o.y);
                o.z = fmaf(beta, d4.z, o.z); o.w = fmaf(beta, d4.w, o.w);
            }
            *(float4*)(C + cb) = o;
        }
    }
}

template<int BM, int BN, int BK, int TM, int TN, bool TB, bool HAS_A2, bool HAS_D>
__launch_bounds__(256)
__global__ void mm_kernel(const float* __restrict__ A, const float* __restrict__ Bmat,
                          const float* __restrict__ A2, const float* __restrict__ Dmat,
                          float* __restrict__ C, int M, int N, int K, float alpha, float beta)
{
    mm_body<BM,BN,BK,TM,TN,TB,HAS_A2,HAS_D>(A, Bmat, A2, Dmat, C, M, N, K, alpha, beta);
}

// batched pair via blockIdx.z
template<int BM, int BN, int BK, int TM, int TN, bool TB, bool HAS_A2, bool HAS_D>
__launch_bounds__(256)
__global__ void mm2_kernel(const float* A0, const float* A1,
                           const float* B0, const float* B1,
                           const float* D0, const float* D1,
                           float* C0, float* C1,
                           int M, int N, int K, float alpha, float beta)
{
    const int z = blockIdx.z;
    mm_body<BM,BN,BK,TM,TN,TB,HAS_A2,HAS_D>(z ? A1 : A0, z ? B1 : B0, nullptr,
                                            z ? D1 : D0, z ? C1 : C0,
                                            M, N, K, alpha, beta);
}

// ---------------------------------------------------------------------------
// Newton-Schulz helpers
// ---------------------------------------------------------------------------
__global__ void norm2_kernel(const float* __restrict__ W, float* __restrict__ out, int n)
{
    float ss = 0.f;
    for (int i = (blockIdx.x * 256 + threadIdx.x) * 4; i < n; i += gridDim.x * 256 * 4) {
        float4 w = *(const float4*)(W + i);
        ss += w.x * w.x + w.y * w.y + w.z * w.z + w.w * w.w;
    }
#pragma unroll
    for (int off = 32; off > 0; off >>= 1) ss += __shfl_xor(ss, off);
    __shared__ float red[4];
    if ((threadIdx.x & 63) == 0) red[threadIdx.x >> 6] = ss;
    __syncthreads();
    if (threadIdx.x == 0) atomicAdd(out, red[0] + red[1] + red[2] + red[3]);
}

__global__ void scale_kernel(const float* __restrict__ W, const float* __restrict__ norm2,
                             float* __restrict__ X, int n)
{
    const float s = 1.0f / (sqrtf(*norm2) + 1e-8f);
    const int i = (blockIdx.x * 256 + threadIdx.x) * 4;
    if (i < n) {
        float4 w = *(const float4*)(W + i);
        w.x *= s; w.y *= s; w.z *= s; w.w *= s;
        *(float4*)(X + i) = w;
    }
}

// ---------------------------------------------------------------------------
// Scan v4: TWO recurrence steps per global round-trip (k=2 blocking).
//
//   z_t    = s_{t-1} (O z_{t-1}) + u_t                 (s = rms scale of z)
//   z_{t+1}= s_t c + u_{t+1},  c = s_{t-1} (O^2 z_{t-1}) + (O u_t)
//
// Producers can't know s_t (global sumsq of z_t), so each WG publishes its
// 16-dim chunk of c PLUS a scalar partial p_g = sum z_t^2 over its dims.
// Consumers: every wave redundantly polls all 64 partials with lanes 0-15
// (4 shuffles + broadcast -> s_t, NO extra barrier), reconstructs
// z_{t+1} = s_t*c + u_{t+1} per-thread, stages it, and proceeds.
// O rows AND O^2 rows live in registers (128 VGPRs); O*u_t is computed in the
// same matvec pass from an LDS-staged u row, so no U' precompute is needed.
// Round-trips per step are HALVED; protocol (4-slot ring, bit0 validity tag,
// canary poison, poison->vmcnt(0)->publish ordering) is unchanged.
// Re-poison is issued early (slot dead as soon as this round's poll succeeds)
// and QS stores moved after the publish, so vmcnt(0) drains nearly nothing.
// ---------------------------------------------------------------------------
#define CANARY 0xAAAAAAAAu
#define HPITCH 36           // 32-float chunk + 4 pad: banks 4*(kg+j) mod 32 distinct
#define RNDS   (T_DIM/2)    // 2048 rounds, 2 steps each
#define SLOTW  1152         // per-batch slot: 1024 c-words + 64 p-words + pad
#define RINGW  (4*B_DIM*SLOTW)   // 18432 words = 72 KB

__global__ void scan_init_kernel(unsigned int* __restrict__ zring)
{
    const int i = blockIdx.x * 256 + threadIdx.x;
    if (i < RINGW) zring[i] = CANARY;
}

__launch_bounds__(256, 1)
__global__ void scan_kernel(const float* __restrict__ O1,    // O_lh      [1024][1024]
                            const float* __restrict__ O2,    // O_lh^2    [1024][1024]
                            const float* __restrict__ ident, // [1024]
                            const float* __restrict__ U,     // [B][T][C]
                            float* __restrict__ QS,          // [B][T][C]
                            unsigned int* __restrict__ zring)// [4][B][SLOTW]
{
    __shared__ float sZ[32 * HPITCH];   // reconstructed z (padded chunks)
    __shared__ float sU[32 * HPITCH];   // u row for the O*u matvec
    __shared__ float sP[4 * 48];        // per-wave dot partials: [wave][8rg*6]
    __shared__ float sS[4];             // per-wave sumsq of z

    const int tid  = threadIdx.x;
    const int wg   = blockIdx.x;         // 256 WGs
    const int b    = wg >> 6;            // batch
    const int g    = wg & 63;            // dim-group
    const int d0   = g * 16;
    const int rg   = tid & 7;
    const int kg   = tid >> 3;           // 0..31
    const int wid  = tid >> 6;
    const int lane = tid & 63;

    // ---- O rows (d0+2rg, d0+2rg+1) and O^2 rows, k in [kg*32, +32) -> regs
    float o0[32], o1[32], w0[32], w1[32];
    {
        const float* r0p = O1 + (size_t)(d0 + 2 * rg) * C_DIM + kg * 32;
        const float* r1p = r0p + C_DIM;
        const float* r2p = O2 + (size_t)(d0 + 2 * rg) * C_DIM + kg * 32;
        const float* r3p = r2p + C_DIM;
#pragma unroll
        for (int j = 0; j < 8; ++j) {
            float4 a = *(const float4*)(r0p + j * 4);
            o0[j*4+0] = a.x; o0[j*4+1] = a.y; o0[j*4+2] = a.z; o0[j*4+3] = a.w;
            float4 c = *(const float4*)(r1p + j * 4);
            o1[j*4+0] = c.x; o1[j*4+1] = c.y; o1[j*4+2] = c.z; o1[j*4+3] = c.w;
            float4 e = *(const float4*)(r2p + j * 4);
            w0[j*4+0] = e.x; w0[j*4+1] = e.y; w0[j*4+2] = e.z; w0[j*4+3] = e.w;
            float4 f = *(const float4*)(r3p + j * 4);
            w1[j*4+0] = f.x; w1[j*4+1] = f.y; w1[j*4+2] = f.z; w1[j*4+3] = f.w;
        }
    }

    const int bbase = b * SLOTW;
    float zmid_hold = 0.f;   // producer lanes: z_{2r-1}[d] carried to next round

    for (int r = 1; r <= RNDS + 1; ++r) {
        // ---- prefetch full u rows (independent; hide under the poll)
        float4 uin = make_float4(0.f, 0.f, 0.f, 0.f);  // u_{2r-2} (reconstruct)
        float4 upv = make_float4(0.f, 0.f, 0.f, 0.f);  // u_{2r-1} (O*u matvec)
        if (r >= 2)
            uin = *(const float4*)(U + ((size_t)b * T_DIM + (2*r - 3)) * C_DIM + tid * 4);
        if (r <= RNDS)
            upv = *(const float4*)(U + ((size_t)b * T_DIM + (2*r - 2)) * C_DIM + tid * 4);

        // ---- poll previous round's publish; reconstruct z boundary
        float s_bnd = 1.0f;
        float4 z4;
        if (r == 1) {
            z4 = *(const float4*)(ident + tid * 4);    // z_0, consumed raw
        } else {
            unsigned long long q0, q1, q2 = ~0ull, q3 = ~0ull;
            unsigned int* sb = zring + ((r - 1) & 3) * (B_DIM * SLOTW) + bbase;
            unsigned long long* pc = (unsigned long long*)(sb + tid * 4);
            unsigned long long* pp = (unsigned long long*)(sb + 1024 + (lane & 15) * 4);
            const bool hp = (lane < 16);
            for (;;) {
                q0 = __hip_atomic_load(pc,     __ATOMIC_RELAXED, __HIP_MEMORY_SCOPE_AGENT);
                q1 = __hip_atomic_load(pc + 1, __ATOMIC_RELAXED, __HIP_MEMORY_SCOPE_AGENT);
                if (hp) {
                    q2 = __hip_atomic_load(pp,     __ATOMIC_RELAXED, __HIP_MEMORY_SCOPE_AGENT);
                    q3 = __hip_atomic_load(pp + 1, __ATOMIC_RELAXED, __HIP_MEMORY_SCOPE_AGENT);
                }
                const unsigned long long m = q0 & q1 & q2 & q3;
                if (m & (m >> 32) & 1ull) break;
                __builtin_amdgcn_s_sleep(1);
            }
            // s_{2r-3} from the 64 published partials (per-wave, no barrier)
            float psum = 0.f;
            if (hp)
                psum = __uint_as_float((unsigned)q2) + __uint_as_float((unsigned)(q2 >> 32))
                     + __uint_as_float((unsigned)q3) + __uint_as_float((unsigned)(q3 >> 32));
            psum += __shfl_xor(psum, 1);
            psum += __shfl_xor(psum, 2);
            psum += __shfl_xor(psum, 4);
            psum += __shfl_xor(psum, 8);
            psum = __shfl(psum, 0);
            s_bnd = 1.0f / sqrtf(psum * (1.0f / 1024.0f) + 1e-6f);
            // z_{2r-2} = s_{2r-3} * c + u_{2r-2}
            z4.x = fmaf(s_bnd, __uint_as_float((unsigned)q0),         uin.x);
            z4.y = fmaf(s_bnd, __uint_as_float((unsigned)(q0 >> 32)), uin.y);
            z4.z = fmaf(s_bnd, __uint_as_float((unsigned)q1),         uin.z);
            z4.w = fmaf(s_bnd, __uint_as_float((unsigned)(q1 >> 32)), uin.w);
        }

        // ---- early re-poison of slot (r+1)&3 (dead once this poll succeeded);
        //      drains during compute so the pre-publish vmcnt(0) is cheap
        if (r <= RNDS && tid < 16) {
            unsigned int* pn = zring + ((r + 1) & 3) * (B_DIM * SLOTW) + bbase;
            __hip_atomic_store(pn + d0 + tid, CANARY,
                               __ATOMIC_RELAXED, __HIP_MEMORY_SCOPE_AGENT);
            if (tid == 0)
                __hip_atomic_store(pn + 1024 + g, CANARY,
                                   __ATOMIC_RELAXED, __HIP_MEMORY_SCOPE_AGENT);
        }

        // ---- stage z and u (same-wave consumers -> no barrier needed)
        *(float4*)(sZ + kg * HPITCH + rg * 4) = z4;
        if (r <= RNDS)
            *(float4*)(sU + kg * HPITCH + rg * 4) = upv;

        // sumsq of staged z -> per-wave reduce -> sS
        float ss = z4.x * z4.x + z4.y * z4.y + z4.z * z4.z + z4.w * z4.w;
#pragma unroll
        for (int off = 32; off > 0; off >>= 1) ss += __shfl_xor(ss, off);
        if (lane == 0) sS[wid] = ss;

        // value for the lagged qs write of z_{2r-3} (valid r>=2)
        const float qheld = s_bnd * zmid_hold;

        // ---- triple matvec: rows x {z (O), z (O^2), u (O)}
        float aa0 = 0.f, aa1 = 0.f, ab0 = 0.f, ab1 = 0.f, ac0 = 0.f, ac1 = 0.f;
        if (r <= RNDS) {
            const float* zb = sZ + kg * HPITCH;
            const float* ub = sU + kg * HPITCH;
#pragma unroll
            for (int j = 0; j < 8; ++j) {
                float4 h4 = *(const float4*)(zb + j * 4);
                float4 u4 = *(const float4*)(ub + j * 4);
                aa0 = fmaf(o0[j*4+0], h4.x, aa0); aa0 = fmaf(o0[j*4+1], h4.y, aa0);
                aa0 = fmaf(o0[j*4+2], h4.z, aa0); aa0 = fmaf(o0[j*4+3], h4.w, aa0);
                aa1 = fmaf(o1[j*4+0], h4.x, aa1); aa1 = fmaf(o1[j*4+1], h4.y, aa1);
                aa1 = fmaf(o1[j*4+2], h4.z, aa1); aa1 = fmaf(o1[j*4+3], h4.w, aa1);
                ab0 = fmaf(w0[j*4+0], h4.x, ab0); ab0 = fmaf(w0[j*4+1], h4.y, ab0);
                ab0 = fmaf(w0[j*4+2], h4.z, ab0); ab0 = fmaf(w0[j*4+3], h4.w, ab0);
                ab1 = fmaf(w1[j*4+0], h4.x, ab1); ab1 = fmaf(w1[j*4+1], h4.y, ab1);
                ab1 = fmaf(w1[j*4+2], h4.z, ab1); ab1 = fmaf(w1[j*4+3], h4.w, ab1);
                ac0 = fmaf(o0[j*4+0], u4.x, ac0); ac0 = fmaf(o0[j*4+1], u4.y, ac0);
                ac0 = fmaf(o0[j*4+2], u4.z, ac0); ac0 = fmaf(o0[j*4+3], u4.w, ac0);
                ac1 = fmaf(o1[j*4+0], u4.x, ac1); ac1 = fmaf(o1[j*4+1], u4.y, ac1);
                ac1 = fmaf(o1[j*4+2], u4.z, ac1); ac1 = fmaf(o1[j*4+3], u4.w, ac1);
            }
            // reduce over the wave's 8 k-groups (tid bits 3..5)
            aa0 += __shfl_xor(aa0, 8);  aa1 += __shfl_xor(aa1, 8);
            ab0 += __shfl_xor(ab0, 8);  ab1 += __shfl_xor(ab1, 8);
            ac0 += __shfl_xor(ac0, 8);  ac1 += __shfl_xor(ac1, 8);
            aa0 += __shfl_xor(aa0, 16); aa1 += __shfl_xor(aa1, 16);
            ab0 += __shfl_xor(ab0, 16); ab1 += __shfl_xor(ab1, 16);
            ac0 += __shfl_xor(ac0, 16); ac1 += __shfl_xor(ac1, 16);
            aa0 += __shfl_xor(aa0, 32); aa1 += __shfl_xor(aa1, 32);
            ab0 += __shfl_xor(ab0, 32); ab1 += __shfl_xor(ab1, 32);
            ac0 += __shfl_xor(ac0, 32); ac1 += __shfl_xor(ac1, 32);
            if (lane < 8) {
                float* sp = sP + wid * 48 + rg * 6;
                sp[0] = aa0; sp[1] = aa1; sp[2] = ab0;
                sp[3] = ab1; sp[4] = ac0; sp[5] = ac1;
            }
        }
        __syncthreads();   // sP + sS + cross-wave sZ/sU visible

        const float sumsq = sS[0] + sS[1] + sS[2] + sS[3];
        const float s_in = (r == 1) ? 1.0f
                                    : 1.0f / sqrtf(sumsq * (1.0f / 1024.0f) + 1e-6f);

        if (r <= RNDS && tid < 16) {
            // gather dots for own dim d = d0 + tid
            const int rgi = tid >> 1, sel = tid & 1;
            float da = 0.f, db = 0.f, dc = 0.f;
#pragma unroll
            for (int w2 = 0; w2 < 4; ++w2) {
                const float* sp = sP + w2 * 48 + rgi * 6;
                da += sp[sel]; db += sp[2 + sel]; dc += sp[4 + sel];
            }
            const int k = d0 + tid;
            const float un = sU[(k >> 5) * HPITCH + (k & 31)];   // u_{2r-1}[d]
            const float zm = fmaf(s_in, da, un);                 // z_{2r-1}[d]
            const float co = fmaf(s_in, db, dc);                 // c chunk
            float pv = zm * zm;                                  // partial ||z_{2r-1}||^2
            pv += __shfl_xor(pv, 1); pv += __shfl_xor(pv, 2);
            pv += __shfl_xor(pv, 4); pv += __shfl_xor(pv, 8);
            zmid_hold = zm;
            asm volatile("" ::: "memory");
            __builtin_amdgcn_s_waitcnt(0x0F70);   // vmcnt(0): poisons drained
            asm volatile("" ::: "memory");
            unsigned int* sb = zring + (r & 3) * (B_DIM * SLOTW) + bbase;
            __hip_atomic_store(sb + d0 + tid, __float_as_uint(co) | 1u,
                               __ATOMIC_RELAXED, __HIP_MEMORY_SCOPE_AGENT);
            if (tid == 0)
                __hip_atomic_store(sb + 1024 + g, __float_as_uint(pv) | 1u,
                                   __ATOMIC_RELAXED, __HIP_MEMORY_SCOPE_AGENT);
        }

        // ---- qs writes AFTER publish (off the vmcnt(0) critical path)
        if (r >= 2 && tid < 16) {
            const int k = d0 + tid;
            QS[((size_t)b * T_DIM + (2*r - 4)) * C_DIM + k] = qheld;
            QS[((size_t)b * T_DIM + (2*r - 3)) * C_DIM + k] =
                s_in * sZ[(k >> 5) * HPITCH + (k & 31)];
        }
        // no bottom barrier: waves that race ahead spin on the next poll,
        // which cannot succeed until our wave-0 publish above has issued.
    }
}

// ---------------------------------------------------------------------------
extern "C" void kernel_launch(void* const* d_in, const int* in_sizes, int n_in,
                              void* d_out, int out_size, void* d_ws, size_t ws_size,
                              hipStream_t stream)
{
    (void)in_sizes; (void)n_in; (void)out_size;

    const float* x     = (const float*)d_in[0];
    const float* Wq    = (const float*)d_in[1];
    const float* Wv    = (const float*)d_in[2];
    const float* Wc    = (const float*)d_in[3];
    const float* ident = (const float*)d_in[4];
    const float* Wlh   = (const float*)d_in[5];
    const float* Wrh   = (const float*)d_in[6];

    char* ws = (char*)d_ws;
    float*        norm2 = (float*)(ws + 256);
    unsigned int* zring = (unsigned int*)(ws + 4096);  // 72 KB (RINGW words)
    float* Xa_lh = (float*)(ws + (size_t)128 * 1024);
    float* Xb_lh = Xa_lh + 1048576;
    float* Xa_rh = Xb_lh + 1048576;
    float* Xb_rh = Xa_rh + 1048576;
    float* G     = Xb_rh + 1048576;

    const size_t batched_need = (size_t)128 * 1024 + 6u * 4194304u + 67108864u;
    const bool batched = ws_size >= batched_need;

    float* G2 = G + (batched ? 1048576 : 0);           // only valid if batched
    float* V  = G + (batched ? 2 * 1048576 : 1048576); // 64 MB

    float* out   = (float*)d_out;
    float* Ybuf  = out;          // first half: u, then Y
    float* QSbuf = out + BTC;    // second half: q, then qs

    const int n2 = C_DIM * C_DIM;

    hipMemsetAsync(ws, 0, 4096, stream);   // norm2 accumulators

    // --- Newton-Schulz prescale
    norm2_kernel<<<dim3(256), dim3(256), 0, stream>>>(Wlh, &norm2[0], n2);
    norm2_kernel<<<dim3(256), dim3(256), 0, stream>>>(Wrh, &norm2[1], n2);
    scale_kernel<<<dim3(1024), dim3(256), 0, stream>>>(Wlh, &norm2[0], Xa_lh, n2);
    scale_kernel<<<dim3(1024), dim3(256), 0, stream>>>(Wrh, &norm2[1], Xa_rh, n2);

    // --- ring init: poison everything (round 1 reads ident directly)
    scan_init_kernel<<<dim3(72), dim3(256), 0, stream>>>(zring);

    // --- Newton-Schulz iterations: X <- 1.5X - 0.5 (X X^T) X
    float* Xl = Xa_lh; float* Xln = Xb_lh;
    float* Xr = Xa_rh; float* Xrn = Xb_rh;
    const dim3 blk(256);
    if (batched) {
        const dim3 g64b(16, 16, 2);
        for (int it = 0; it < 12; ++it) {
            mm2_kernel<64,64,16,4,4,true ,false,false><<<g64b, blk, 0, stream>>>(
                Xl, Xr, Xl, Xr, nullptr, nullptr, G, G2, 1024, 1024, 1024, 1.0f, 0.0f);
            mm2_kernel<64,64,16,4,4,false,false,true ><<<g64b, blk, 0, stream>>>(
                G, G2, Xl, Xr, Xl, Xr, Xln, Xrn, 1024, 1024, 1024, -0.5f, 1.5f);
            float* tmp;
            tmp = Xl; Xl = Xln; Xln = tmp;
            tmp = Xr; Xr = Xrn; Xrn = tmp;
        }
    } else {
        const dim3 g64(16, 16);
        for (int it = 0; it < 12; ++it) {
            mm_kernel<64,64,16,4,4,true ,false,false><<<g64, blk, 0, stream>>>(
                Xl, Xl, nullptr, nullptr, G, 1024, 1024, 1024, 1.0f, 0.0f);
            mm_kernel<64,64,16,4,4,false,false,true ><<<g64, blk, 0, stream>>>(
                G, Xl, nullptr, Xl, Xln, 1024, 1024, 1024, -0.5f, 1.5f);
            mm_kernel<64,64,16,4,4,true ,false,false><<<g64, blk, 0, stream>>>(
                Xr, Xr, nullptr, nullptr, G, 1024, 1024, 1024, 1.0f, 0.0f);
            mm_kernel<64,64,16,4,4,false,false,true ><<<g64, blk, 0, stream>>>(
                G, Xr, nullptr, Xr, Xrn, 1024, 1024, 1024, -0.5f, 1.5f);
            float* tmp;
            tmp = Xl; Xl = Xln; Xln = tmp;
            tmp = Xr; Xr = Xrn; Xrn = tmp;
        }
    }
    // Xl = O_lh, Xr = O_rh

    // --- O_lh^2 for the 2-step scan blocking (G is free after NS)
    mm_kernel<64,64,16,4,4,false,false,false><<<dim3(16,16), blk, 0, stream>>>(
        Xl, Xl, nullptr, nullptr, G, 1024, 1024, 1024, 1.0f, 0.0f);

    // --- big GEMMs: q = x Wq^T (into QS half) and v = x Wv^T, batched; then
    //     u = q O_rh^T (into Y half)
    const dim3 gbig(C_DIM / 128, BT / 128);
    const dim3 gbig2(C_DIM / 128, BT / 128, 2);
    mm2_kernel<128,128,16,8,8,true,false,false><<<gbig2, blk, 0, stream>>>(
        x, x, Wq, Wv, nullptr, nullptr, QSbuf, V, BT, C_DIM, C_DIM, 1.0f, 0.0f);
    mm_kernel<128,128,16,8,8,true,false,false><<<gbig, blk, 0, stream>>>(
        QSbuf, Xr, nullptr, nullptr, Ybuf, BT, C_DIM, C_DIM, 1.0f, 0.0f);

    // --- sequential scan (persistent, spin-on-data, 2 steps per round-trip)
    scan_kernel<<<dim3(256), dim3(256), 0, stream>>>(Xl, G, ident, Ybuf, QSbuf, zring);

    // --- Y = (qs * v) Wc^T  (overwrites u region)
    mm_kernel<128,128,16,8,8,true,true,false><<<gbig, blk, 0, stream>>>(
        QSbuf, Wc, V, nullptr, Ybuf, BT, C_DIM, C_DIM, 1.0f, 0.0f);
}

// Round 3
// 10004.484 us; speedup vs baseline: 1.8825x; 1.8825x over previous
//
#include <hip/hip_runtime.h>
#include <math.h>

#define B_DIM 4
#define T_DIM 4096
#define C_DIM 1024
#define BT    (B_DIM*T_DIM)              // 16384
#define BTC   ((size_t)BT*(size_t)C_DIM) // 16777216

// ---------------------------------------------------------------------------
// Generic fp32 tiled matmul body (shared by single and batched wrappers).
//   TB=1: C[m,n] = sum_k A[m,k]*B[n,k]      (B stored [N,K] row-major)
//   TB=0: C[m,n] = sum_k A[m,k]*B[k,n]
//   HAS_A2: A_eff[m,k] = A[m,k]*A2[m,k]
//   out = alpha*acc + (HAS_D ? beta*D[m,n] : 0)
//   lda: row stride (elements) of A/A2 — 2048 GEMMs the even/odd rows of a
//        [16384][1024] matrix.
// ---------------------------------------------------------------------------
template<int BM, int BN, int BK, int TM, int TN, bool TB, bool HAS_A2, bool HAS_D>
__device__ __forceinline__ void mm_body(const float* __restrict__ A,
                                        const float* __restrict__ Bmat,
                                        const float* __restrict__ A2,
                                        const float* __restrict__ Dmat,
                                        float* __restrict__ C,
                                        int M, int N, int K, int lda,
                                        float alpha, float beta)
{
    constexpr int NG = TN / 4;
    __shared__ float As[BK][BM + 4];
    __shared__ float Bs[BK][BN + 4];

    const int tid = threadIdx.x;
    const int m0 = blockIdx.y * BM;
    const int n0 = blockIdx.x * BN;
    const int tx = tid & 15;
    const int ty = tid >> 4;

    float acc[TM][TN];
#pragma unroll
    for (int i = 0; i < TM; ++i)
#pragma unroll
        for (int j = 0; j < TN; ++j) acc[i][j] = 0.f;

    for (int k0 = 0; k0 < K; k0 += BK) {
        {
            const int r0 = tid >> 2;
            const int kq = (tid & 3) * 4;
#pragma unroll
            for (int r = 0; r < BM; r += 64) {
                const int row = r + r0;
                float4 a = *(const float4*)(A + (size_t)(m0 + row) * lda + k0 + kq);
                if (HAS_A2) {
                    float4 a2 = *(const float4*)(A2 + (size_t)(m0 + row) * lda + k0 + kq);
                    a.x *= a2.x; a.y *= a2.y; a.z *= a2.z; a.w *= a2.w;
                }
                As[kq + 0][row] = a.x; As[kq + 1][row] = a.y;
                As[kq + 2][row] = a.z; As[kq + 3][row] = a.w;
            }
        }
        if (TB) {
            const int r0 = tid >> 2;
            const int kq = (tid & 3) * 4;
#pragma unroll
            for (int r = 0; r < BN; r += 64) {
                const int row = r + r0;
                float4 b = *(const float4*)(Bmat + (size_t)(n0 + row) * K + k0 + kq);
                Bs[kq + 0][row] = b.x; Bs[kq + 1][row] = b.y;
                Bs[kq + 2][row] = b.z; Bs[kq + 3][row] = b.w;
            }
        } else {
            constexpr int CPR = BN / 4;
            constexpr int RPP = 256 / CPR;
            const int rr = tid / CPR;
            const int cc = (tid % CPR) * 4;
#pragma unroll
            for (int r = 0; r < BK; r += RPP) {
                float4 b = *(const float4*)(Bmat + (size_t)(k0 + r + rr) * N + n0 + cc);
                *(float4*)(&Bs[r + rr][cc]) = b;
            }
        }
        __syncthreads();

#pragma unroll
        for (int kk = 0; kk < BK; ++kk) {
            float a[TM], b[TN];
#pragma unroll
            for (int i = 0; i < TM; i += 4)
                *(float4*)(&a[i]) = *(const float4*)(&As[kk][ty * TM + i]);
#pragma unroll
            for (int g = 0; g < NG; ++g)
                *(float4*)(&b[g * 4]) = *(const float4*)(&Bs[kk][g * (BN / 2) + tx * 4]);
#pragma unroll
            for (int i = 0; i < TM; ++i)
#pragma unroll
                for (int j = 0; j < TN; ++j)
                    acc[i][j] = fmaf(a[i], b[j], acc[i][j]);
        }
        __syncthreads();
    }

#pragma unroll
    for (int i = 0; i < TM; ++i) {
        const size_t rbase = (size_t)(m0 + ty * TM + i) * N + n0;
#pragma unroll
        for (int g = 0; g < NG; ++g) {
            const size_t cb = rbase + g * (BN / 2) + tx * 4;
            float4 o;
            o.x = alpha * acc[i][g * 4 + 0];
            o.y = alpha * acc[i][g * 4 + 1];
            o.z = alpha * acc[i][g * 4 + 2];
            o.w = alpha * acc[i][g * 4 + 3];
            if (HAS_D) {
                float4 d4 = *(const float4*)(Dmat + cb);
                o.x = fmaf(beta, d4.x, o.x); o.y = fmaf(beta, d4.y, o.y);
                o.z = fmaf(beta, d4.z, o.z); o.w = fmaf(beta, d4.w, o.w);
            }
            *(float4*)(C + cb) = o;
        }
    }
}

template<int BM, int BN, int BK, int TM, int TN, bool TB, bool HAS_A2, bool HAS_D>
__launch_bounds__(256)
__global__ void mm_kernel(const float* __restrict__ A, const float* __restrict__ Bmat,
                          const float* __restrict__ A2, const float* __restrict__ Dmat,
                          float* __restrict__ C, int M, int N, int K, int lda,
                          float alpha, float beta)
{
    mm_body<BM,BN,BK,TM,TN,TB,HAS_A2,HAS_D>(A, Bmat, A2, Dmat, C, M, N, K, lda, alpha, beta);
}

// batched pair via blockIdx.z
template<int BM, int BN, int BK, int TM, int TN, bool TB, bool HAS_A2, bool HAS_D>
__launch_bounds__(256)
__global__ void mm2_kernel(const float* A0, const float* A1,
                           const float* B0, const float* B1,
                           const float* D0, const float* D1,
                           float* C0, float* C1,
                           int M, int N, int K, int lda, float alpha, float beta)
{
    const int z = blockIdx.z;
    mm_body<BM,BN,BK,TM,TN,TB,HAS_A2,HAS_D>(z ? A1 : A0, z ? B1 : B0, nullptr,
                                            z ? D1 : D0, z ? C1 : C0,
                                            M, N, K, lda, alpha, beta);
}

// ---------------------------------------------------------------------------
// Newton-Schulz helpers
// ---------------------------------------------------------------------------
__global__ void norm2_kernel(const float* __restrict__ W, float* __restrict__ out, int n)
{
    float ss = 0.f;
    for (int i = (blockIdx.x * 256 + threadIdx.x) * 4; i < n; i += gridDim.x * 256 * 4) {
        float4 w = *(const float4*)(W + i);
        ss += w.x * w.x + w.y * w.y + w.z * w.z + w.w * w.w;
    }
#pragma unroll
    for (int off = 32; off > 0; off >>= 1) ss += __shfl_xor(ss, off);
    __shared__ float red[4];
    if ((threadIdx.x & 63) == 0) red[threadIdx.x >> 6] = ss;
    __syncthreads();
    if (threadIdx.x == 0) atomicAdd(out, red[0] + red[1] + red[2] + red[3]);
}

__global__ void scale_kernel(const float* __restrict__ W, const float* __restrict__ norm2,
                             float* __restrict__ X, int n)
{
    const float s = 1.0f / (sqrtf(*norm2) + 1e-8f);
    const int i = (blockIdx.x * 256 + threadIdx.x) * 4;
    if (i < n) {
        float4 w = *(const float4*)(W + i);
        w.x *= s; w.y *= s; w.z *= s; w.w *= s;
        *(float4*)(X + i) = w;
    }
}

// ---------------------------------------------------------------------------
// Scan v6 — see theory block. k=2 with pre-norm c publish (exact math) and
// per-wave c-only polls so heavy compute overlaps producer straggler spread.
// ---------------------------------------------------------------------------
#define CANARY 0xAAAAAAAAu
#define HPITCH 36             // 32-float chunk + 4 pad
#define RNDS   (T_DIM/2)      // 2048 rounds, 2 steps each
#define SLOTW  1088           // 1024 c-words + 64 partial words
#define RINGW  (4*B_DIM*SLOTW)

__global__ void scan_init_kernel(unsigned int* __restrict__ zring)
{
    const int i = blockIdx.x * 256 + threadIdx.x;   // 68 blocks
    if (i < RINGW) zring[i] = CANARY;
}

__launch_bounds__(256, 1)
__global__ void scan_kernel(const float* __restrict__ O1,    // O_lh    [1024][1024]
                            const float* __restrict__ O2,    // O_lh^2  [1024][1024]
                            const float* __restrict__ ident, // [1024]
                            const float* __restrict__ U,     // [B][T][C]
                            const float* __restrict__ Ue,    // [B][T/2][C] evenU@O1^T
                            const float* __restrict__ Uo,    // [B][T/2][C] oddU@O1^T
                            float* __restrict__ QS,          // [B][T][C]
                            unsigned int* __restrict__ zring)// [4][B][SLOTW]
{
    __shared__ float sC[32 * HPITCH];   // staged c (z_0 at r=1)
    __shared__ float sUo[32 * HPITCH];  // staged (O u_rec) row
    __shared__ float sP[4 * 48];        // per-wave dot partials [wave][8rg*6]
    __shared__ float sS[12];            // per-wave {CC,CU,UU}

    const int tid  = threadIdx.x;
    const int wg   = blockIdx.x;         // 256 WGs
    const int b    = wg >> 6;            // batch
    const int g    = wg & 63;            // dim-group
    const int d0   = g * 16;
    const int rg   = tid & 7;
    const int kg   = tid >> 3;           // 0..31
    const int wid  = tid >> 6;
    const int lane = tid & 63;

    // ---- O1 rows (d0+2rg, d0+2rg+1) and O2 rows, k in [kg*32, +32) -> regs
    float o0[32], o1[32], w0[32], w1[32];
    {
        const float* r0p = O1 + (size_t)(d0 + 2 * rg) * C_DIM + kg * 32;
        const float* r1p = r0p + C_DIM;
        const float* r2p = O2 + (size_t)(d0 + 2 * rg) * C_DIM + kg * 32;
        const float* r3p = r2p + C_DIM;
#pragma unroll
        for (int j = 0; j < 8; ++j) {
            float4 a = *(const float4*)(r0p + j * 4);
            o0[j*4+0] = a.x; o0[j*4+1] = a.y; o0[j*4+2] = a.z; o0[j*4+3] = a.w;
            float4 c = *(const float4*)(r1p + j * 4);
            o1[j*4+0] = c.x; o1[j*4+1] = c.y; o1[j*4+2] = c.z; o1[j*4+3] = c.w;
            float4 e = *(const float4*)(r2p + j * 4);
            w0[j*4+0] = e.x; w0[j*4+1] = e.y; w0[j*4+2] = e.z; w0[j*4+3] = e.w;
            float4 f = *(const float4*)(r3p + j * 4);
            w1[j*4+0] = f.x; w1[j*4+1] = f.y; w1[j*4+2] = f.z; w1[j*4+3] = f.w;
        }
    }

    const int bbase = b * SLOTW;
    float zhold = 0.f;     // tid<16: z_{2r-1}[own d] carried to next round

    for (int r = 1; r <= RNDS + 1; ++r) {
        // ---- prefetch (independent of the ring; hides under the poll)
        float4 urec4 = make_float4(0.f, 0.f, 0.f, 0.f);  // U row 2r-3 (odd)
        float4 uo4   = make_float4(0.f, 0.f, 0.f, 0.f);  // Uo row r-2
        float u_mid_s = 0.f, cm_s = 0.f, urec_s = 0.f;
        if (r >= 2) {
            urec4 = *(const float4*)(U + ((size_t)b * T_DIM + (2*r - 3)) * C_DIM + tid * 4);
            if (r <= RNDS)
                uo4 = *(const float4*)(Uo + ((size_t)b * (T_DIM/2) + (r - 2)) * C_DIM + tid * 4);
            if (tid < 16)
                urec_s = U[((size_t)b * T_DIM + (2*r - 3)) * C_DIM + d0 + tid];
        }
        if (r <= RNDS && tid < 16) {
            u_mid_s = U[((size_t)b * T_DIM + (2*r - 2)) * C_DIM + d0 + tid];
            cm_s    = Ue[((size_t)b * (T_DIM/2) + (r - 1)) * C_DIM + d0 + tid];
        }

        // ---- poll own 4 c-words only (fast exit -> per-wave overlap)
        float4 c4;
        unsigned int* sb_prev = zring + ((r - 1) & 3) * (B_DIM * SLOTW) + bbase;
        if (r == 1) {
            c4 = *(const float4*)(ident + tid * 4);      // z_0 as c; s1p=1, u_rec=0
        } else {
            unsigned long long q0, q1;
            unsigned long long* p = (unsigned long long*)(sb_prev + tid * 4);
            for (;;) {
                q0 = __hip_atomic_load(p,     __ATOMIC_RELAXED, __HIP_MEMORY_SCOPE_AGENT);
                q1 = __hip_atomic_load(p + 1, __ATOMIC_RELAXED, __HIP_MEMORY_SCOPE_AGENT);
                const unsigned long long m = q0 & q1;
                if (m & (m >> 32) & 1ull) break;
                __builtin_amdgcn_s_sleep(1);
            }
            c4.x = __uint_as_float((unsigned int)q0);
            c4.y = __uint_as_float((unsigned int)(q0 >> 32));
            c4.z = __uint_as_float((unsigned int)q1);
            c4.w = __uint_as_float((unsigned int)(q1 >> 32));
        }

        // ---- early re-poison of slot (r+1)&3
        if (r <= RNDS && tid < 16) {
            unsigned int* pn = zring + ((r + 1) & 3) * (B_DIM * SLOTW) + bbase;
            __hip_atomic_store(pn + d0 + tid, CANARY,
                               __ATOMIC_RELAXED, __HIP_MEMORY_SCOPE_AGENT);
            if (tid == 0)
                __hip_atomic_store(pn + 1024 + g, CANARY,
                                   __ATOMIC_RELAXED, __HIP_MEMORY_SCOPE_AGENT);
        }

        // ---- stage c and (O u_rec) (same-wave consumers -> no barrier)
        *(float4*)(sC  + kg * HPITCH + rg * 4) = c4;
        *(float4*)(sUo + kg * HPITCH + rg * 4) = uo4;

        // ---- local norm partials: CC=Σc², CU=Σc·u_rec, UU=Σu_rec²
        float cc = c4.x*c4.x + c4.y*c4.y + c4.z*c4.z + c4.w*c4.w;
        float cu = c4.x*urec4.x + c4.y*urec4.y + c4.z*urec4.z + c4.w*urec4.w;
        float uu = urec4.x*urec4.x + urec4.y*urec4.y + urec4.z*urec4.z + urec4.w*urec4.w;
#pragma unroll
        for (int off = 32; off > 0; off >>= 1) {
            cc += __shfl_xor(cc, off);
            cu += __shfl_xor(cu, off);
            uu += __shfl_xor(uu, off);
        }
        if (lane == 0) { sS[wid*3+0] = cc; sS[wid*3+1] = cu; sS[wid*3+2] = uu; }

        // ---- triple matvec on raw operands: {c x O1, c x O2, Uo-row x O1}
        if (r <= RNDS) {
            const float* zb = sC  + kg * HPITCH;
            const float* ub = sUo + kg * HPITCH;
            float aa0 = 0.f, aa1 = 0.f, ab0 = 0.f, ab1 = 0.f, ac0 = 0.f, ac1 = 0.f;
#pragma unroll
            for (int j = 0; j < 8; ++j) {
                float4 h4 = *(const float4*)(zb + j * 4);
                float4 u4 = *(const float4*)(ub + j * 4);
                aa0 = fmaf(o0[j*4+0], h4.x, aa0); aa0 = fmaf(o0[j*4+1], h4.y, aa0);
                aa0 = fmaf(o0[j*4+2], h4.z, aa0); aa0 = fmaf(o0[j*4+3], h4.w, aa0);
                aa1 = fmaf(o1[j*4+0], h4.x, aa1); aa1 = fmaf(o1[j*4+1], h4.y, aa1);
                aa1 = fmaf(o1[j*4+2], h4.z, aa1); aa1 = fmaf(o1[j*4+3], h4.w, aa1);
                ab0 = fmaf(w0[j*4+0], h4.x, ab0); ab0 = fmaf(w0[j*4+1], h4.y, ab0);
                ab0 = fmaf(w0[j*4+2], h4.z, ab0); ab0 = fmaf(w0[j*4+3], h4.w, ab0);
                ab1 = fmaf(w1[j*4+0], h4.x, ab1); ab1 = fmaf(w1[j*4+1], h4.y, ab1);
                ab1 = fmaf(w1[j*4+2], h4.z, ab1); ab1 = fmaf(w1[j*4+3], h4.w, ab1);
                ac0 = fmaf(o0[j*4+0], u4.x, ac0); ac0 = fmaf(o0[j*4+1], u4.y, ac0);
                ac0 = fmaf(o0[j*4+2], u4.z, ac0); ac0 = fmaf(o0[j*4+3], u4.w, ac0);
                ac1 = fmaf(o1[j*4+0], u4.x, ac1); ac1 = fmaf(o1[j*4+1], u4.y, ac1);
                ac1 = fmaf(o1[j*4+2], u4.z, ac1); ac1 = fmaf(o1[j*4+3], u4.w, ac1);
            }
            aa0 += __shfl_xor(aa0, 8);  aa1 += __shfl_xor(aa1, 8);
            ab0 += __shfl_xor(ab0, 8);  ab1 += __shfl_xor(ab1, 8);
            ac0 += __shfl_xor(ac0, 8);  ac1 += __shfl_xor(ac1, 8);
            aa0 += __shfl_xor(aa0, 16); aa1 += __shfl_xor(aa1, 16);
            ab0 += __shfl_xor(ab0, 16); ab1 += __shfl_xor(ab1, 16);
            ac0 += __shfl_xor(ac0, 16); ac1 += __shfl_xor(ac1, 16);
            aa0 += __shfl_xor(aa0, 32); aa1 += __shfl_xor(aa1, 32);
            ab0 += __shfl_xor(ab0, 32); ab1 += __shfl_xor(ab1, 32);
            ac0 += __shfl_xor(ac0, 32); ac1 += __shfl_xor(ac1, 32);
            if (lane < 8) {
                float* sp = sP + wid * 48 + rg * 6;
                sp[0] = aa0; sp[1] = aa1; sp[2] = ab0;
                sp[3] = ab1; sp[4] = ac0; sp[5] = ac1;
            }
        }

        // ---- wave 0 only: poll the 64 norm partials AFTER the matvec
        float s1p = 1.0f;
        if (r >= 2 && wid == 0 && lane < 16) {
            unsigned long long q2, q3;
            unsigned long long* pp = (unsigned long long*)(sb_prev + 1024 + lane * 4);
            for (;;) {
                q2 = __hip_atomic_load(pp,     __ATOMIC_RELAXED, __HIP_MEMORY_SCOPE_AGENT);
                q3 = __hip_atomic_load(pp + 1, __ATOMIC_RELAXED, __HIP_MEMORY_SCOPE_AGENT);
                const unsigned long long m = q2 & q3;
                if (m & (m >> 32) & 1ull) break;
                __builtin_amdgcn_s_sleep(1);
            }
            float psum = __uint_as_float((unsigned)q2) + __uint_as_float((unsigned)(q2 >> 32))
                       + __uint_as_float((unsigned)q3) + __uint_as_float((unsigned)(q3 >> 32));
            psum += __shfl_xor(psum, 1);
            psum += __shfl_xor(psum, 2);
            psum += __shfl_xor(psum, 4);
            psum += __shfl_xor(psum, 8);
            s1p = 1.0f / sqrtf(psum * (1.0f / 1024.0f) + 1e-6f);
        }
        __syncthreads();   // sS + sP + cross-wave sC/sUo visible

        if (tid < 16) {
            const int k = d0 + tid;
            float s0 = 1.0f;
            if (r >= 2) {
                const float CC = sS[0] + sS[3] + sS[6] + sS[9];
                const float CU = sS[1] + sS[4] + sS[7] + sS[10];
                const float UU = sS[2] + sS[5] + sS[8] + sS[11];
                float nz = fmaf(s1p * s1p, CC, fmaf(2.0f * s1p, CU, UU));
                nz = fmaxf(nz, 0.0f);
                s0 = 1.0f / sqrtf(nz * (1.0f / 1024.0f) + 1e-6f);
            }
            const float zhold_prev = zhold;   // z_{2r-3}[d] from last round

            if (r <= RNDS) {
                const int rgi = tid >> 1, sel = tid & 1;
                float da = 0.f, db = 0.f, dc = 0.f;
#pragma unroll
                for (int w2 = 0; w2 < 4; ++w2) {
                    const float* sp = sP + w2 * 48 + rgi * 6;
                    da += sp[sel]; db += sp[2 + sel]; dc += sp[4 + sel];
                }
                const float a2r = sUo[(k >> 5) * HPITCH + (k & 31)];      // (O u_rec)[d]
                const float zmid = fmaf(s0, fmaf(s1p, da, a2r), u_mid_s); // z_{2r-1}[d]
                const float cpub = fmaf(s0, fmaf(s1p, db, dc), cm_s);     // (O z_{2r-1})[d]
                float pv = zmid * zmid;
                pv += __shfl_xor(pv, 1); pv += __shfl_xor(pv, 2);
                pv += __shfl_xor(pv, 4); pv += __shfl_xor(pv, 8);

                asm volatile("" ::: "memory");
                __builtin_amdgcn_s_waitcnt(0x0F70);   // vmcnt(0): poisons drained
                asm volatile("" ::: "memory");
                unsigned int* sb = zring + (r & 3) * (B_DIM * SLOTW) + bbase;
                __hip_atomic_store(sb + d0 + tid, __float_as_uint(cpub) | 1u,
                                   __ATOMIC_RELAXED, __HIP_MEMORY_SCOPE_AGENT);
                if (tid == 0)
                    __hip_atomic_store(sb + 1024 + g, __float_as_uint(pv) | 1u,
                                       __ATOMIC_RELAXED, __HIP_MEMORY_SCOPE_AGENT);
                zhold = zmid;
            }

            // ---- QS outputs AFTER publish (off the critical path)
            if (r >= 2) {
                // h_{2r-3} = s_{2r-3} * z_{2r-3}   (s1p is exactly s_{2r-3})
                QS[((size_t)b * T_DIM + (2*r - 4)) * C_DIM + k] = s1p * zhold_prev;
                // h_{2r-2} = s_{2r-2} * z_{2r-2},  z_{2r-2} = s1p*c + u_rec
                QS[((size_t)b * T_DIM + (2*r - 3)) * C_DIM + k] =
                    s0 * fmaf(s1p, sC[(k >> 5) * HPITCH + (k & 31)], urec_s);
            }
        }
        // no bottom barrier: racing waves spin on the next poll, which cannot
        // succeed until wave 0's publish above has issued.
    }
}

// ---------------------------------------------------------------------------
extern "C" void kernel_launch(void* const* d_in, const int* in_sizes, int n_in,
                              void* d_out, int out_size, void* d_ws, size_t ws_size,
                              hipStream_t stream)
{
    (void)in_sizes; (void)n_in; (void)out_size;

    const float* x     = (const float*)d_in[0];
    const float* Wq    = (const float*)d_in[1];
    const float* Wv    = (const float*)d_in[2];
    const float* Wc    = (const float*)d_in[3];
    const float* ident = (const float*)d_in[4];
    const float* Wlh   = (const float*)d_in[5];
    const float* Wrh   = (const float*)d_in[6];

    char* ws = (char*)d_ws;
    float*        norm2 = (float*)(ws + 256);
    unsigned int* zring = (unsigned int*)(ws + 4096);   // 68 KB (RINGW words)
    float* Xa_lh = (float*)(ws + (size_t)128 * 1024);
    float* Xb_lh = Xa_lh + 1048576;
    float* Xa_rh = Xb_lh + 1048576;
    float* Xb_rh = Xa_rh + 1048576;
    float* G     = Xb_rh + 1048576;

    const size_t batched_need = (size_t)128 * 1024 + 6u * 4194304u + 67108864u;
    const bool batched = ws_size >= batched_need;

    float* G2 = G + (batched ? 1048576 : 0);           // only valid if batched
    float* V  = G + (batched ? 2 * 1048576 : 1048576); // 64 MB
    float* Ue = V;             // 32 MB, alive only during the scan
    float* Uo = V + 8388608;   // 32 MB, alive only during the scan

    float* out   = (float*)d_out;
    float* Ybuf  = out;          // first half: u, then Y
    float* QSbuf = out + BTC;    // second half: q, then qs

    const int n2 = C_DIM * C_DIM;

    hipMemsetAsync(ws, 0, 4096, stream);   // norm2 accumulators

    // --- Newton-Schulz prescale
    norm2_kernel<<<dim3(256), dim3(256), 0, stream>>>(Wlh, &norm2[0], n2);
    norm2_kernel<<<dim3(256), dim3(256), 0, stream>>>(Wrh, &norm2[1], n2);
    scale_kernel<<<dim3(1024), dim3(256), 0, stream>>>(Wlh, &norm2[0], Xa_lh, n2);
    scale_kernel<<<dim3(1024), dim3(256), 0, stream>>>(Wrh, &norm2[1], Xa_rh, n2);

    // --- ring init: poison everything (round 1 reads ident directly)
    scan_init_kernel<<<dim3(68), dim3(256), 0, stream>>>(zring);

    // --- Newton-Schulz iterations: X <- 1.5X - 0.5 (X X^T) X
    float* Xl = Xa_lh; float* Xln = Xb_lh;
    float* Xr = Xa_rh; float* Xrn = Xb_rh;
    const dim3 blk(256);
    if (batched) {
        const dim3 g64b(16, 16, 2);
        for (int it = 0; it < 12; ++it) {
            mm2_kernel<64,64,16,4,4,true ,false,false><<<g64b, blk, 0, stream>>>(
                Xl, Xr, Xl, Xr, nullptr, nullptr, G, G2, 1024, 1024, 1024, 1024, 1.0f, 0.0f);
            mm2_kernel<64,64,16,4,4,false,false,true ><<<g64b, blk, 0, stream>>>(
                G, G2, Xl, Xr, Xl, Xr, Xln, Xrn, 1024, 1024, 1024, 1024, -0.5f, 1.5f);
            float* tmp;
            tmp = Xl; Xl = Xln; Xln = tmp;
            tmp = Xr; Xr = Xrn; Xrn = tmp;
        }
    } else {
        const dim3 g64(16, 16);
        for (int it = 0; it < 12; ++it) {
            mm_kernel<64,64,16,4,4,true ,false,false><<<g64, blk, 0, stream>>>(
                Xl, Xl, nullptr, nullptr, G, 1024, 1024, 1024, 1024, 1.0f, 0.0f);
            mm_kernel<64,64,16,4,4,false,false,true ><<<g64, blk, 0, stream>>>(
                G, Xl, nullptr, Xl, Xln, 1024, 1024, 1024, 1024, -0.5f, 1.5f);
            mm_kernel<64,64,16,4,4,true ,false,false><<<g64, blk, 0, stream>>>(
                Xr, Xr, nullptr, nullptr, G, 1024, 1024, 1024, 1024, 1.0f, 0.0f);
            mm_kernel<64,64,16,4,4,false,false,true ><<<g64, blk, 0, stream>>>(
                G, Xr, nullptr, Xr, Xrn, 1024, 1024, 1024, 1024, -0.5f, 1.5f);
            float* tmp;
            tmp = Xl; Xl = Xln; Xln = tmp;
            tmp = Xr; Xr = Xrn; Xrn = tmp;
        }
    }
    // Xl = O_lh, Xr = O_rh

    // --- O_lh^2 for the 2-step scan blocking (G free after NS)
    mm_kernel<64,64,16,4,4,false,false,false><<<dim3(16,16), blk, 0, stream>>>(
        Xl, Xl, nullptr, nullptr, G, 1024, 1024, 1024, 1024, 1.0f, 0.0f);

    // --- big GEMMs: q = x Wq^T (into QS half); u = q O_rh^T (into Y half)
    const dim3 gbig(C_DIM / 128, BT / 128);
    mm_kernel<128,128,16,8,8,true,false,false><<<gbig, blk, 0, stream>>>(
        x, Wq, nullptr, nullptr, QSbuf, BT, C_DIM, C_DIM, C_DIM, 1.0f, 0.0f);
    mm_kernel<128,128,16,8,8,true,false,false><<<gbig, blk, 0, stream>>>(
        QSbuf, Xr, nullptr, nullptr, Ybuf, BT, C_DIM, C_DIM, C_DIM, 1.0f, 0.0f);

    // --- scan precomputes: Ue = evenU@O1^T, Uo = oddU@O1^T (lda=2048 strides
    //     every other row; TB=true so output dim d matches (O1 u)[d])
    mm2_kernel<128,128,16,8,8,true,false,false><<<dim3(8, 64, 2), blk, 0, stream>>>(
        Ybuf, Ybuf + C_DIM, Xl, Xl, nullptr, nullptr, Ue, Uo,
        8192, C_DIM, C_DIM, 2048, 1.0f, 0.0f);

    // --- sequential scan (persistent, spin-on-data, 2 steps per round trip)
    scan_kernel<<<dim3(256), dim3(256), 0, stream>>>(Xl, G, ident, Ybuf, Ue, Uo,
                                                     QSbuf, zring);

    // --- v = x Wv^T (into V, overwriting the dead Ue/Uo), then
    //     Y = (qs * v) Wc^T  (overwrites u region)
    mm_kernel<128,128,16,8,8,true,false,false><<<gbig, blk, 0, stream>>>(
        x, Wv, nullptr, nullptr, V, BT, C_DIM, C_DIM, C_DIM, 1.0f, 0.0f);
    mm_kernel<128,128,16,8,8,true,true,false><<<gbig, blk, 0, stream>>>(
        QSbuf, Wc, V, nullptr, Ybuf, BT, C_DIM, C_DIM, C_DIM, 1.0f, 0.0f);
}